// Round 15
// baseline (159.008 us; speedup 1.0000x reference)
//
#include <hip/hip_runtime.h>
#include <hip/hip_bf16.h>
#include <math.h>

#define NUM_CLASSES 81
#define TOP_K       200
#define NBINS       4096
#define CAND_MAX    512
#define NSORT       512
#define CONF_THRESH 0.05f
#define NMS_THRESH  0.45f
#define CSTRIDE     16     // one 64B line per counter (R2: false-sharing fix)
#define CBLOCKS     2048   // collect grid: 8 blocks/CU -> 32 waves/CU TLP
#define SCAP        512    // per-block staging (mean ~202, +22 sigma)
#define FTHREADS    512    // finalize block: thread i owns sort slot i
#define FREP        4      // R15 PROBE: internal idempotent reps to surface
                           // finalize in rocprof top-5 (reverted next round)
// Collection threshold: 4076/4096 (exact in f32). E[count] = 65536*20/4096 = 320
// per column, sigma ~= 17.9; [200, 512] window is -6.7 / +10.7 sigma.
#define T0F (4076.0f / 4096.0f)
// Exact threshold test for fl32(inter/denom) > 0.45f:
//   q > M where M = midpoint(0.45f, nextafter) = 0x1.CCCCCDp-2.
#define IOU_M 0x1.CCCCCDp-2

// ---------------------------------------------------------------------------
// Kernel 0: zero the padded counters (replaces hipMemsetAsync, ~96us runtime fill).
// ---------------------------------------------------------------------------
__global__ __launch_bounds__(256) void zero_counts_kernel(
    int* __restrict__ counts, int nbc)
{
    int t = blockIdx.x * blockDim.x + threadIdx.x;
    if (t < nbc) counts[t * CSTRIDE] = 0;
}

// ---------------------------------------------------------------------------
// Kernel 1: coalesced pass over conf; 8 outstanding float4 loads/iter.
// R8/R14: collect is HBM-BW-bound at ~27us (ILP 4->8 was null). Unchanged.
// conf flat index e = (b*A + a)*81 + c -> q = e/81 = b*A + a.
// ---------------------------------------------------------------------------
__global__ __launch_bounds__(256) void collect_kernel(
    const float4* __restrict__ conf4,
    unsigned long long* __restrict__ cand,   // [nbc][CAND_MAX]
    int* __restrict__ counts,                // [nbc * CSTRIDE]
    unsigned AC,                             // A * 81
    unsigned N4,                             // total floats / 4
    int nbc,                                 // B * 81
    int ashift)                              // log2(A) if A pow2, else 0
{
    __shared__ int s_bcnt[NUM_CLASSES * 8];          // per-bucket local count
    __shared__ int s_bbase[NUM_CLASSES * 8];         // reserved global base
    __shared__ unsigned long long s_key[SCAP];
    __shared__ unsigned s_meta[SCAP];                // bc | (local_pos << 16)
    __shared__ int s_total;

    const int tid = threadIdx.x;

    for (int i = tid; i < nbc; i += 256) s_bcnt[i] = 0;
    if (tid == 0) s_total = 0;
    __syncthreads();

    auto process = [&](float4 v4, unsigned t) {
        float vs[4] = {v4.x, v4.y, v4.z, v4.w};
#pragma unroll
        for (int j = 0; j < 4; ++j) {
            float v = vs[j];
            if (v > T0F) {                       // ~0.5% of elements
                unsigned e = 4u * t + (unsigned)j;
                unsigned a, b, c;
                if (ashift) {                    // wave-uniform branch
                    unsigned q = e / NUM_CLASSES;        // magic mul (constexpr)
                    c = e - q * NUM_CLASSES;
                    a = q & ((1u << ashift) - 1u);
                    b = q >> ashift;
                } else {                         // generic (runtime div) path
                    b = e / AC;
                    unsigned rem = e - b * AC;
                    a = rem / NUM_CLASSES;
                    c = rem - a * NUM_CLASSES;
                }
                unsigned bc  = b * NUM_CLASSES + c;
                unsigned long long key =
                    ((unsigned long long)__float_as_uint(v) << 32) |
                    (unsigned)(~a);
                int sp = atomicAdd(&s_total, 1);
                if (sp < SCAP) {
                    int p = atomicAdd(&s_bcnt[bc], 1);
                    s_key[sp]  = key;
                    s_meta[sp] = bc | ((unsigned)p << 16);
                } else {
                    // staging overflow (never on this data): direct global path
                    int gp = atomicAdd(&counts[bc * CSTRIDE], 1);
                    if (gp < CAND_MAX)
                        cand[(size_t)bc * CAND_MAX + gp] = key;
                }
            }
        }
    };

    // ---- Stream a contiguous chunk: 8 independent loads per iteration ----
    unsigned per = (N4 + gridDim.x - 1) / gridDim.x;
    unsigned lo  = blockIdx.x * per;
    unsigned hi  = lo + per; if (hi > N4) hi = N4;
    unsigned last = N4 - 1;

    for (unsigned t = lo + tid; t < hi; t += 2048) {
        unsigned ti[8];
        float4 vv[8];
#pragma unroll
        for (int s = 0; s < 8; ++s) {
            ti[s] = t + 256u * s;
            vv[s] = conf4[ti[s] < hi ? ti[s] : last];  // clamped loads safe;
        }                                              // OOB guarded below
        process(vv[0], t);
#pragma unroll
        for (int s = 1; s < 8; ++s)
            if (ti[s] < hi) process(vv[s], ti[s]);
    }
    __syncthreads();

    // ---- Reserve per-bucket ranges: one global atomic per non-empty bucket ----
    for (int i = tid; i < nbc; i += 256) {
        int cloc = s_bcnt[i];
        if (cloc > 0) s_bbase[i] = atomicAdd(&counts[i * CSTRIDE], cloc);
    }
    __syncthreads();

    // ---- Scatter staged candidates with plain stores ----
    int total = s_total < SCAP ? s_total : SCAP;
    for (int s = tid; s < total; s += 256) {
        unsigned meta = s_meta[s];
        unsigned bc   = meta & 0xFFFFu;
        unsigned p    = meta >> 16;
        long long g   = (long long)s_bbase[bc] + (long long)p;
        if (g < CAND_MAX)
            cand[(size_t)bc * CAND_MAX + g] = s_key[s];
    }
}

// ---------------------------------------------------------------------------
// Kernel 2: per-(b,c) finalize == R14 logic, wrapped in an FREP-times
// idempotent repetition (R15 PROBE). Every rep recomputes from the same
// read-only inputs and overwrites `out` with identical values, so output is
// unchanged; the dispatch duration ~4x surfaces finalize's PMC counters in
// the top-5 (harness poison fills occupy it otherwise). dur delta /3 = F.
// ---------------------------------------------------------------------------
__global__ __launch_bounds__(FTHREADS) void finalize_kernel(
    const float* __restrict__ loc,      // [B, A, 4]
    const float* __restrict__ conf,     // [B, A*81] (fallback path only)
    const float* __restrict__ anchors,  // [A, 4]
    const unsigned long long* __restrict__ cand,
    const int* __restrict__ counts,
    float* __restrict__ out,
    int A, int use_ws)
{
    __shared__ unsigned long long sk[NSORT];       // 4 KB (big-j phases + fallback)
    __shared__ unsigned s_scratch[NBINS];          // 16 KB, multi-purpose
    __shared__ int s_cnt;
    __shared__ int s_tbin;

    int* hist = (int*)s_scratch;
    unsigned (*sup)[8] = (unsigned(*)[8])s_scratch;        // [200][8] = 1600 u32
    float* bx0 = (float*)(s_scratch + 1600);
    float* by0 = (float*)(s_scratch + 1800);
    float* bx1 = (float*)(s_scratch + 2000);
    float* by1 = (float*)(s_scratch + 2200);
    float* bar = (float*)(s_scratch + 2400);
    float* bsc = (float*)(s_scratch + 2600);
    unsigned* s_keep = s_scratch + 2800;                    // [8]
    unsigned* s_rm   = s_scratch + 2808;                    // [8] rowmask

    const int tid = threadIdx.x;
    const int bc  = blockIdx.x;
    const int b   = bc / NUM_CLASSES;
    const int c   = bc % NUM_CLASSES;

    for (int rep = 0; rep < FREP; ++rep) {
    __syncthreads();   // protect LDS reuse across reps

    // ---- Get this thread's sort element into register v ----
    unsigned long long v = 0ULL;
    int cnt = -1;
    if (use_ws) {
        cnt = counts[bc * CSTRIDE];
        if (cnt >= TOP_K && cnt <= CAND_MAX) {
            if (tid < cnt) v = cand[(size_t)bc * CAND_MAX + tid];
        } else {
            cnt = -1;  // trigger fallback
        }
    }

    if (cnt < 0) {
        // ---- Fallback: strided scan (+ exact histogram select if needed) ----
        const float* cp = conf + (size_t)b * A * NUM_CLASSES + c;
        if (tid == 0) s_cnt = 0;
        __syncthreads();
        for (int a = tid; a < A; a += FTHREADS) {
            float val = cp[(size_t)a * NUM_CLASSES];
            if (val > T0F) {
                int pos = atomicAdd(&s_cnt, 1);
                if (pos < CAND_MAX)
                    sk[pos] = ((unsigned long long)__float_as_uint(val) << 32) |
                              (unsigned)(~(unsigned)a);
            }
        }
        __syncthreads();
        cnt = s_cnt;
        if (cnt < TOP_K || cnt > CAND_MAX) {
            for (int i = tid; i < NBINS; i += FTHREADS) hist[i] = 0;
            __syncthreads();
            for (int a = tid; a < A; a += FTHREADS) {
                float val = cp[(size_t)a * NUM_CLASSES];
                if (val > CONF_THRESH) {
                    int bin = (int)(val * (float)NBINS);
                    bin = bin < 0 ? 0 : (bin > NBINS - 1 ? NBINS - 1 : bin);
                    atomicAdd(&hist[bin], 1);
                }
            }
            __syncthreads();
            if (tid == 0) {
                int acc = 0, t = NBINS - 1;
                for (; t > 0; --t) { acc += hist[t]; if (acc >= TOP_K) break; }
                s_tbin = t;
                s_cnt  = 0;
            }
            __syncthreads();
            int tb = s_tbin;
            for (int a = tid; a < A; a += FTHREADS) {
                float val = cp[(size_t)a * NUM_CLASSES];
                if (val > CONF_THRESH) {
                    int bin = (int)(val * (float)NBINS);
                    bin = bin < 0 ? 0 : (bin > NBINS - 1 ? NBINS - 1 : bin);
                    if (bin >= tb) {
                        int pos = atomicAdd(&s_cnt, 1);
                        if (pos < CAND_MAX)
                            sk[pos] = ((unsigned long long)__float_as_uint(val) << 32) |
                                      (unsigned)(~(unsigned)a);
                    }
                }
            }
            __syncthreads();
            cnt = s_cnt < CAND_MAX ? s_cnt : CAND_MAX;
        }
        // pad and move to register
        for (int i = cnt + tid; i < NSORT; i += FTHREADS) sk[i] = 0ULL;
        __syncthreads();
        v = sk[tid];
    }

    // ---- Hybrid bitonic sort, descending: register CE via shuffle (j<64),
    //      LDS CE only for j>=64 ----
    for (int k = 2; k <= NSORT; k <<= 1) {
        for (int j = k >> 1; j > 0; j >>= 1) {
            bool keepMax = ((tid & k) == 0) ^ ((tid & j) != 0);
            unsigned long long u;
            if (j >= 64) {
                sk[tid] = v;
                __syncthreads();
                u = sk[tid ^ j];
                __syncthreads();
            } else {
                unsigned hi32 = __shfl_xor((unsigned)(v >> 32), j, 64);
                unsigned lo32 = __shfl_xor((unsigned)(v & 0xFFFFFFFFu), j, 64);
                u = ((unsigned long long)hi32 << 32) | lo32;
            }
            v = keepMax ? (v > u ? v : u) : (v < u ? v : u);
        }
    }

    // ---- Decode top-200 (f32 ops in reference order; no FMA contraction),
    //      and zero sup/keep/rowmask in parallel ----
    for (int i = tid; i < 1600; i += FTHREADS) s_scratch[i] = 0;   // sup
    if (tid < 8)  s_keep[tid] = 0;
    if (tid >= 8 && tid < 16) s_rm[tid - 8] = 0;
    if (tid < TOP_K) {
        unsigned long long key = v;
        float sc = 0.f, x0 = 0.f, y0 = 0.f, x1 = 0.f, y1 = 0.f;
        if (key != 0ULL) {
            sc = __uint_as_float((unsigned)(key >> 32));
            unsigned idx = ~(unsigned)(key & 0xFFFFFFFFu);
            const float* lp = loc + ((size_t)b * A + idx) * 4;
            const float* ap = anchors + (size_t)idx * 4;
            float l0 = lp[0], l1 = lp[1], l2 = lp[2], l3 = lp[3];
            float acx = ap[0], acy = ap[1], aw = ap[2], ah = ap[3];
            float cx = __fadd_rn(acx, __fmul_rn(__fmul_rn(l0, 0.1f), aw));
            float cy = __fadd_rn(acy, __fmul_rn(__fmul_rn(l1, 0.1f), ah));
            float ew = (float)exp((double)__fmul_rn(l2, 0.2f));
            float eh = (float)exp((double)__fmul_rn(l3, 0.2f));
            float w  = __fmul_rn(aw, ew);
            float h  = __fmul_rn(ah, eh);
            float hw = __fmul_rn(w, 0.5f), hh = __fmul_rn(h, 0.5f);
            x0 = __fsub_rn(cx, hw); y0 = __fsub_rn(cy, hh);
            x1 = __fadd_rn(cx, hw); y1 = __fadd_rn(cy, hh);
        }
        bx0[tid] = x0; by0[tid] = y0; bx1[tid] = x1; by1[tid] = y1;
        bar[tid] = __fmul_rn(__fsub_rn(x1, x0), __fsub_rn(y1, y0));
        bsc[tid] = sc;
    }
    __syncthreads();

    // ---- Build suppression bitmask + rowmask; division-free exact IoU test ----
    if (tid < TOP_K && bsc[tid] > CONF_THRESH)
        atomicOr(&s_keep[tid >> 5], 1u << (tid & 31));
    {
        const int wave = tid >> 6, lane = tid & 63;       // 8 waves
        for (int i = wave; i < TOP_K - 1; i += FTHREADS / 64) {
            float ix0 = bx0[i], iy0 = by0[i], ix1 = bx1[i], iy1 = by1[i];
            float iar = bar[i];
            for (int j = i + 1 + lane; j < TOP_K; j += 64) {
                float ltx = fmaxf(ix0, bx0[j]);
                float lty = fmaxf(iy0, by0[j]);
                float rbx = fminf(ix1, bx1[j]);
                float rby = fminf(iy1, by1[j]);
                float iw  = __fsub_rn(rbx, ltx);
                float ih  = __fsub_rn(rby, lty);
                if (iw > 0.f && ih > 0.f) {       // else inter==0 -> iou==0
                    float inter = __fmul_rn(iw, ih);
                    float denom = __fadd_rn(
                        __fsub_rn(__fadd_rn(iar, bar[j]), inter), 1e-9f);
                    if ((double)inter > IOU_M * (double)denom) {
                        atomicOr(&sup[i][j >> 5], 1u << (j & 31));
                        atomicOr(&s_rm[i >> 5], 1u << (i & 31));
                    }
                }
            }
        }
    }
    __syncthreads();

    // ---- Keep propagation, wave 0: shfl keep test + conditional sup AND,
    //      iterating only rows present in rowmask. ----
    if (tid < 64) {
        unsigned keepw = (tid < 7) ? s_keep[tid] : 0u;
        unsigned act0 = s_rm[0], act1 = s_rm[1], act2 = s_rm[2], act3 = s_rm[3];
        unsigned act4 = s_rm[4], act5 = s_rm[5], act6 = s_rm[6];
#define PROP_BITS(ACT, BASE)                                           \
        while (ACT) {                                                  \
            int i = (BASE) + (__ffs(ACT) - 1);                         \
            unsigned kw = __shfl(keepw, i >> 5, 64);                   \
            if ((kw >> (i & 31)) & 1u) {                               \
                if (tid < 7) keepw &= ~sup[i][tid];                    \
            }                                                          \
            ACT &= ACT - 1;                                            \
        }
        PROP_BITS(act0, 0)
        PROP_BITS(act1, 32)
        PROP_BITS(act2, 64)
        PROP_BITS(act3, 96)
        PROP_BITS(act4, 128)
        PROP_BITS(act5, 160)
        PROP_BITS(act6, 192)
#undef PROP_BITS
        if (tid < 7) s_keep[tid] = keepw;
    }
    __syncthreads();

    // ---- Write outputs (identical every rep) ----
    if (tid < TOP_K) {
        int kp = (s_keep[tid >> 5] >> (tid & 31)) & 1u;
        size_t lb = ((size_t)bc * TOP_K + tid) * 4;
        out[lb + 0] = kp ? bx0[tid] : 0.f;
        out[lb + 1] = kp ? by0[tid] : 0.f;
        out[lb + 2] = kp ? bx1[tid] : 0.f;
        out[lb + 3] = kp ? by1[tid] : 0.f;
        out[(size_t)gridDim.x * TOP_K * 4 + (size_t)bc * TOP_K + tid] =
            kp ? bsc[tid] : 0.f;
    }
    }  // rep loop
}

extern "C" void kernel_launch(void* const* d_in, const int* in_sizes, int n_in,
                              void* d_out, int out_size, void* d_ws, size_t ws_size,
                              hipStream_t stream) {
    const float* loc     = (const float*)d_in[0];
    const float* conf    = (const float*)d_in[1];
    const float* anchors = (const float*)d_in[2];
    float* out = (float*)d_out;

    int A = in_sizes[2] / 4;                 // anchors: [A,4]
    int B = in_sizes[0] / (A * 4);           // preds_loc: [B,A,4]
    int BC = B * NUM_CLASSES;

    int ashift = 0;
    if ((A & (A - 1)) == 0) { while ((1 << ashift) != A) ++ashift; }

    size_t counts_bytes = (size_t)BC * CSTRIDE * sizeof(int);
    counts_bytes = (counts_bytes + 4095) & ~(size_t)4095;   // align cand region
    size_t cand_bytes = (size_t)BC * CAND_MAX * sizeof(unsigned long long);
    int use_ws = (ws_size >= counts_bytes + cand_bytes && BC <= NUM_CLASSES * 8) ? 1 : 0;

    int* counts = (int*)d_ws;
    unsigned long long* cand = (unsigned long long*)((char*)d_ws + counts_bytes);

    if (use_ws) {
        unsigned AC = (unsigned)A * NUM_CLASSES;
        unsigned N4 = (unsigned)B * AC / 4u;
        zero_counts_kernel<<<(BC + 255) / 256, 256, 0, stream>>>(counts, BC);
        collect_kernel<<<CBLOCKS, 256, 0, stream>>>(
            (const float4*)conf, cand, counts, AC, N4, BC, ashift);
    }

    finalize_kernel<<<BC, FTHREADS, 0, stream>>>(
        loc, conf, anchors, cand, counts, out, A, use_ws);
}

// Round 16
// 74.217 us; speedup vs baseline: 2.1425x; 2.1425x over previous
//
#include <hip/hip_runtime.h>
#include <hip/hip_bf16.h>
#include <math.h>

#define NUM_CLASSES 81
#define TOP_K       200
#define NBINS       4096
#define CAND_MAX    512
#define NSORT       512
#define CONF_THRESH 0.05f
#define NMS_THRESH  0.45f
#define CSTRIDE     16     // one 64B line per counter (R2: false-sharing fix)
#define CBLOCKS     2048   // collect grid: 8 blocks/CU -> 32 waves/CU TLP
#define SCAP        512    // per-block staging (mean ~202, +22 sigma)
#define FTHREADS    512    // finalize block: thread i owns sort slot i
// Collection threshold: 4076/4096 (exact in f32). E[count] = 65536*20/4096 = 320
// per column, sigma ~= 17.9; [200, 512] window is -6.7 / +10.7 sigma.
#define T0F (4076.0f / 4096.0f)
// Exact threshold test for fl32(inter/denom) > 0.45f:
//   quotient > M, M = midpoint(0.45f, nextafterf) = 0x1.CCCCCDp-2. M has 25
//   mantissa bits, denom 24 -> M*(double)denom is EXACT (49 < 53 bits), so
//   the comparison reproduces the f32-divide+compare bit-exactly.
#define IOU_M 0x1.CCCCCDp-2

// ---------------------------------------------------------------------------
// Kernel 0: zero the padded counters (replaces hipMemsetAsync, ~96us runtime fill).
// ---------------------------------------------------------------------------
__global__ __launch_bounds__(256) void zero_counts_kernel(
    int* __restrict__ counts, int nbc)
{
    int t = blockIdx.x * blockDim.x + threadIdx.x;
    if (t < nbc) counts[t * CSTRIDE] = 0;
}

// ---------------------------------------------------------------------------
// Kernel 1: coalesced pass over conf; 8 outstanding float4 loads/iter.
// R8/R14: collect is HBM-BW-bound at ~27us (ILP 4->8 was null). Unchanged.
// conf flat index e = (b*A + a)*81 + c -> q = e/81 = b*A + a.
// ---------------------------------------------------------------------------
__global__ __launch_bounds__(256) void collect_kernel(
    const float4* __restrict__ conf4,
    unsigned long long* __restrict__ cand,   // [nbc][CAND_MAX]
    int* __restrict__ counts,                // [nbc * CSTRIDE]
    unsigned AC,                             // A * 81
    unsigned N4,                             // total floats / 4
    int nbc,                                 // B * 81
    int ashift)                              // log2(A) if A pow2, else 0
{
    __shared__ int s_bcnt[NUM_CLASSES * 8];          // per-bucket local count
    __shared__ int s_bbase[NUM_CLASSES * 8];         // reserved global base
    __shared__ unsigned long long s_key[SCAP];
    __shared__ unsigned s_meta[SCAP];                // bc | (local_pos << 16)
    __shared__ int s_total;

    const int tid = threadIdx.x;

    for (int i = tid; i < nbc; i += 256) s_bcnt[i] = 0;
    if (tid == 0) s_total = 0;
    __syncthreads();

    auto process = [&](float4 v4, unsigned t) {
        float vs[4] = {v4.x, v4.y, v4.z, v4.w};
#pragma unroll
        for (int j = 0; j < 4; ++j) {
            float v = vs[j];
            if (v > T0F) {                       // ~0.5% of elements
                unsigned e = 4u * t + (unsigned)j;
                unsigned a, b, c;
                if (ashift) {                    // wave-uniform branch
                    unsigned q = e / NUM_CLASSES;        // magic mul (constexpr)
                    c = e - q * NUM_CLASSES;
                    a = q & ((1u << ashift) - 1u);
                    b = q >> ashift;
                } else {                         // generic (runtime div) path
                    b = e / AC;
                    unsigned rem = e - b * AC;
                    a = rem / NUM_CLASSES;
                    c = rem - a * NUM_CLASSES;
                }
                unsigned bc  = b * NUM_CLASSES + c;
                unsigned long long key =
                    ((unsigned long long)__float_as_uint(v) << 32) |
                    (unsigned)(~a);
                int sp = atomicAdd(&s_total, 1);
                if (sp < SCAP) {
                    int p = atomicAdd(&s_bcnt[bc], 1);
                    s_key[sp]  = key;
                    s_meta[sp] = bc | ((unsigned)p << 16);
                } else {
                    // staging overflow (never on this data): direct global path
                    int gp = atomicAdd(&counts[bc * CSTRIDE], 1);
                    if (gp < CAND_MAX)
                        cand[(size_t)bc * CAND_MAX + gp] = key;
                }
            }
        }
    };

    // ---- Stream a contiguous chunk: 8 independent loads per iteration ----
    unsigned per = (N4 + gridDim.x - 1) / gridDim.x;
    unsigned lo  = blockIdx.x * per;
    unsigned hi  = lo + per; if (hi > N4) hi = N4;
    unsigned last = N4 - 1;

    for (unsigned t = lo + tid; t < hi; t += 2048) {
        unsigned ti[8];
        float4 vv[8];
#pragma unroll
        for (int s = 0; s < 8; ++s) {
            ti[s] = t + 256u * s;
            vv[s] = conf4[ti[s] < hi ? ti[s] : last];  // clamped loads safe;
        }                                              // OOB guarded below
        process(vv[0], t);
#pragma unroll
        for (int s = 1; s < 8; ++s)
            if (ti[s] < hi) process(vv[s], ti[s]);
    }
    __syncthreads();

    // ---- Reserve per-bucket ranges: one global atomic per non-empty bucket ----
    for (int i = tid; i < nbc; i += 256) {
        int cloc = s_bcnt[i];
        if (cloc > 0) s_bbase[i] = atomicAdd(&counts[i * CSTRIDE], cloc);
    }
    __syncthreads();

    // ---- Scatter staged candidates with plain stores ----
    int total = s_total < SCAP ? s_total : SCAP;
    for (int s = tid; s < total; s += 256) {
        unsigned meta = s_meta[s];
        unsigned bc   = meta & 0xFFFFu;
        unsigned p    = meta >> 16;
        long long g   = (long long)s_bbase[bc] + (long long)p;
        if (g < CAND_MAX)
            cand[(size_t)bc * CAND_MAX + g] = s_key[s];
    }
}

// ---------------------------------------------------------------------------
// Kernel 2: per-(b,c) finalize. R16 (R15 counters: VALUBusy 67% issue-bound,
// bank-conflicts negligible, FETCH small): FREP probe reverted; mask build
// put on an instruction diet — boxes packed as float4 (1 ds_read_b128 + 1
// b32 vs 5 scalar reads + addr calcs) and branchless clamp (fmaxf(..,0) is
// the reference's exact clip; padded-row hazard gone since denom>0 always
// and inter==0 for disjoint). IoU test unchanged (exact f64 midpoint form).
// ---------------------------------------------------------------------------
__global__ __launch_bounds__(FTHREADS) void finalize_kernel(
    const float* __restrict__ loc,      // [B, A, 4]
    const float* __restrict__ conf,     // [B, A*81] (fallback path only)
    const float* __restrict__ anchors,  // [A, 4]
    const unsigned long long* __restrict__ cand,
    const int* __restrict__ counts,
    float* __restrict__ out,
    int A, int use_ws)
{
    __shared__ unsigned long long sk[NSORT];       // 4 KB (big-j phases + fallback)
    __shared__ unsigned s_scratch[NBINS];          // 16 KB, multi-purpose
    __shared__ int s_cnt;
    __shared__ int s_tbin;

    int* hist = (int*)s_scratch;                           // fallback only
    unsigned (*sup)[8] = (unsigned(*)[8])s_scratch;        // [200][8] = 1600 u32
    float4* bbox = (float4*)(s_scratch + 1600);            // [200] float4 (16B-aligned)
    float* bar = (float*)(s_scratch + 2400);               // [200]
    float* bsc = (float*)(s_scratch + 2600);               // [200]
    unsigned* s_keep = s_scratch + 2800;                   // [8]
    unsigned* s_rm   = s_scratch + 2808;                   // [8] rowmask

    const int tid = threadIdx.x;
    const int bc  = blockIdx.x;
    const int b   = bc / NUM_CLASSES;
    const int c   = bc % NUM_CLASSES;

    // ---- Get this thread's sort element into register v ----
    unsigned long long v = 0ULL;
    int cnt = -1;
    if (use_ws) {
        cnt = counts[bc * CSTRIDE];
        if (cnt >= TOP_K && cnt <= CAND_MAX) {
            if (tid < cnt) v = cand[(size_t)bc * CAND_MAX + tid];
        } else {
            cnt = -1;  // trigger fallback
        }
    }

    if (cnt < 0) {
        // ---- Fallback: strided scan (+ exact histogram select if needed) ----
        const float* cp = conf + (size_t)b * A * NUM_CLASSES + c;
        if (tid == 0) s_cnt = 0;
        __syncthreads();
        for (int a = tid; a < A; a += FTHREADS) {
            float val = cp[(size_t)a * NUM_CLASSES];
            if (val > T0F) {
                int pos = atomicAdd(&s_cnt, 1);
                if (pos < CAND_MAX)
                    sk[pos] = ((unsigned long long)__float_as_uint(val) << 32) |
                              (unsigned)(~(unsigned)a);
            }
        }
        __syncthreads();
        cnt = s_cnt;
        if (cnt < TOP_K || cnt > CAND_MAX) {
            for (int i = tid; i < NBINS; i += FTHREADS) hist[i] = 0;
            __syncthreads();
            for (int a = tid; a < A; a += FTHREADS) {
                float val = cp[(size_t)a * NUM_CLASSES];
                if (val > CONF_THRESH) {
                    int bin = (int)(val * (float)NBINS);
                    bin = bin < 0 ? 0 : (bin > NBINS - 1 ? NBINS - 1 : bin);
                    atomicAdd(&hist[bin], 1);
                }
            }
            __syncthreads();
            if (tid == 0) {
                int acc = 0, t = NBINS - 1;
                for (; t > 0; --t) { acc += hist[t]; if (acc >= TOP_K) break; }
                s_tbin = t;
                s_cnt  = 0;
            }
            __syncthreads();
            int tb = s_tbin;
            for (int a = tid; a < A; a += FTHREADS) {
                float val = cp[(size_t)a * NUM_CLASSES];
                if (val > CONF_THRESH) {
                    int bin = (int)(val * (float)NBINS);
                    bin = bin < 0 ? 0 : (bin > NBINS - 1 ? NBINS - 1 : bin);
                    if (bin >= tb) {
                        int pos = atomicAdd(&s_cnt, 1);
                        if (pos < CAND_MAX)
                            sk[pos] = ((unsigned long long)__float_as_uint(val) << 32) |
                                      (unsigned)(~(unsigned)a);
                    }
                }
            }
            __syncthreads();
            cnt = s_cnt < CAND_MAX ? s_cnt : CAND_MAX;
        }
        // pad and move to register
        for (int i = cnt + tid; i < NSORT; i += FTHREADS) sk[i] = 0ULL;
        __syncthreads();
        v = sk[tid];
    }

    // ---- Hybrid bitonic sort, descending: register CE via shuffle (j<64),
    //      LDS CE only for j>=64 ----
    for (int k = 2; k <= NSORT; k <<= 1) {
        for (int j = k >> 1; j > 0; j >>= 1) {
            bool keepMax = ((tid & k) == 0) ^ ((tid & j) != 0);
            unsigned long long u;
            if (j >= 64) {
                sk[tid] = v;
                __syncthreads();
                u = sk[tid ^ j];
                __syncthreads();
            } else {
                unsigned hi32 = __shfl_xor((unsigned)(v >> 32), j, 64);
                unsigned lo32 = __shfl_xor((unsigned)(v & 0xFFFFFFFFu), j, 64);
                u = ((unsigned long long)hi32 << 32) | lo32;
            }
            v = keepMax ? (v > u ? v : u) : (v < u ? v : u);
        }
    }

    // ---- Decode top-200 (f32 ops in reference order; no FMA contraction),
    //      and zero sup/keep/rowmask in parallel ----
    for (int i = tid; i < 1600; i += FTHREADS) s_scratch[i] = 0;   // sup
    if (tid < 8)  s_keep[tid] = 0;
    if (tid >= 8 && tid < 16) s_rm[tid - 8] = 0;
    if (tid < TOP_K) {
        unsigned long long key = v;
        float sc = 0.f, x0 = 0.f, y0 = 0.f, x1 = 0.f, y1 = 0.f;
        if (key != 0ULL) {
            sc = __uint_as_float((unsigned)(key >> 32));
            unsigned idx = ~(unsigned)(key & 0xFFFFFFFFu);
            const float* lp = loc + ((size_t)b * A + idx) * 4;
            const float* ap = anchors + (size_t)idx * 4;
            float l0 = lp[0], l1 = lp[1], l2 = lp[2], l3 = lp[3];
            float acx = ap[0], acy = ap[1], aw = ap[2], ah = ap[3];
            float cx = __fadd_rn(acx, __fmul_rn(__fmul_rn(l0, 0.1f), aw));
            float cy = __fadd_rn(acy, __fmul_rn(__fmul_rn(l1, 0.1f), ah));
            float ew = (float)exp((double)__fmul_rn(l2, 0.2f));
            float eh = (float)exp((double)__fmul_rn(l3, 0.2f));
            float w  = __fmul_rn(aw, ew);
            float h  = __fmul_rn(ah, eh);
            float hw = __fmul_rn(w, 0.5f), hh = __fmul_rn(h, 0.5f);
            x0 = __fsub_rn(cx, hw); y0 = __fsub_rn(cy, hh);
            x1 = __fadd_rn(cx, hw); y1 = __fadd_rn(cy, hh);
        }
        bbox[tid] = make_float4(x0, y0, x1, y1);
        bar[tid] = __fmul_rn(__fsub_rn(x1, x0), __fsub_rn(y1, y0));
        bsc[tid] = sc;
    }
    __syncthreads();

    // ---- Build suppression bitmask + rowmask; packed b128 box read,
    //      branchless clamp, exact f64 midpoint IoU test ----
    if (tid < TOP_K && bsc[tid] > CONF_THRESH)
        atomicOr(&s_keep[tid >> 5], 1u << (tid & 31));
    {
        const int wave = tid >> 6, lane = tid & 63;       // 8 waves
        for (int i = wave; i < TOP_K - 1; i += FTHREADS / 64) {
            float4 bi = bbox[i];
            float iar = bar[i];
            for (int j = i + 1 + lane; j < TOP_K; j += 64) {
                float4 bj = bbox[j];                       // ds_read_b128
                float iw = fmaxf(__fsub_rn(fminf(bi.z, bj.z),
                                           fmaxf(bi.x, bj.x)), 0.f);
                float ih = fmaxf(__fsub_rn(fminf(bi.w, bj.w),
                                           fmaxf(bi.y, bj.y)), 0.f);
                float inter = __fmul_rn(iw, ih);
                float denom = __fadd_rn(
                    __fsub_rn(__fadd_rn(iar, bar[j]), inter), 1e-9f);
                if ((double)inter > IOU_M * (double)denom) {
                    atomicOr(&sup[i][j >> 5], 1u << (j & 31));
                    atomicOr(&s_rm[i >> 5], 1u << (i & 31));
                }
            }
        }
    }
    __syncthreads();

    // ---- Keep propagation, wave 0: shfl keep test + conditional sup AND,
    //      iterating only rows present in rowmask (R13-proven). ----
    if (tid < 64) {
        unsigned keepw = (tid < 7) ? s_keep[tid] : 0u;
        unsigned act0 = s_rm[0], act1 = s_rm[1], act2 = s_rm[2], act3 = s_rm[3];
        unsigned act4 = s_rm[4], act5 = s_rm[5], act6 = s_rm[6];
#define PROP_BITS(ACT, BASE)                                           \
        while (ACT) {                                                  \
            int i = (BASE) + (__ffs(ACT) - 1);                         \
            unsigned kw = __shfl(keepw, i >> 5, 64);                   \
            if ((kw >> (i & 31)) & 1u) {                               \
                if (tid < 7) keepw &= ~sup[i][tid];                    \
            }                                                          \
            ACT &= ACT - 1;                                            \
        }
        PROP_BITS(act0, 0)
        PROP_BITS(act1, 32)
        PROP_BITS(act2, 64)
        PROP_BITS(act3, 96)
        PROP_BITS(act4, 128)
        PROP_BITS(act5, 160)
        PROP_BITS(act6, 192)
#undef PROP_BITS
        if (tid < 7) s_keep[tid] = keepw;
    }
    __syncthreads();

    // ---- Write outputs ----
    if (tid < TOP_K) {
        int kp = (s_keep[tid >> 5] >> (tid & 31)) & 1u;
        float4 bo = bbox[tid];
        size_t lb = ((size_t)bc * TOP_K + tid) * 4;
        out[lb + 0] = kp ? bo.x : 0.f;
        out[lb + 1] = kp ? bo.y : 0.f;
        out[lb + 2] = kp ? bo.z : 0.f;
        out[lb + 3] = kp ? bo.w : 0.f;
        out[(size_t)gridDim.x * TOP_K * 4 + (size_t)bc * TOP_K + tid] =
            kp ? bsc[tid] : 0.f;
    }
}

extern "C" void kernel_launch(void* const* d_in, const int* in_sizes, int n_in,
                              void* d_out, int out_size, void* d_ws, size_t ws_size,
                              hipStream_t stream) {
    const float* loc     = (const float*)d_in[0];
    const float* conf    = (const float*)d_in[1];
    const float* anchors = (const float*)d_in[2];
    float* out = (float*)d_out;

    int A = in_sizes[2] / 4;                 // anchors: [A,4]
    int B = in_sizes[0] / (A * 4);           // preds_loc: [B,A,4]
    int BC = B * NUM_CLASSES;

    int ashift = 0;
    if ((A & (A - 1)) == 0) { while ((1 << ashift) != A) ++ashift; }

    size_t counts_bytes = (size_t)BC * CSTRIDE * sizeof(int);
    counts_bytes = (counts_bytes + 4095) & ~(size_t)4095;   // align cand region
    size_t cand_bytes = (size_t)BC * CAND_MAX * sizeof(unsigned long long);
    int use_ws = (ws_size >= counts_bytes + cand_bytes && BC <= NUM_CLASSES * 8) ? 1 : 0;

    int* counts = (int*)d_ws;
    unsigned long long* cand = (unsigned long long*)((char*)d_ws + counts_bytes);

    if (use_ws) {
        unsigned AC = (unsigned)A * NUM_CLASSES;
        unsigned N4 = (unsigned)B * AC / 4u;
        zero_counts_kernel<<<(BC + 255) / 256, 256, 0, stream>>>(counts, BC);
        collect_kernel<<<CBLOCKS, 256, 0, stream>>>(
            (const float4*)conf, cand, counts, AC, N4, BC, ashift);
    }

    finalize_kernel<<<BC, FTHREADS, 0, stream>>>(
        loc, conf, anchors, cand, counts, out, A, use_ws);
}